// Round 7
// baseline (936.176 us; speedup 1.0000x reference)
//
#include <hip/hip_runtime.h>
#include <float.h>

typedef _Float16 f16;
typedef f16 f16x8 __attribute__((ext_vector_type(8)));
typedef float f32x4 __attribute__((ext_vector_type(4)));
typedef unsigned int u32;

#define NPTS 262144
#define DDIM 128
#define NVQ 6
#define KCODES 512
#define TM 64
#define BLOCKT 256

__device__ __forceinline__ int swz(int row, int grp) {
    return row * DDIM + ((grp ^ (row & 7)) << 3);
}
__device__ __forceinline__ u32 umin32(u32 a, u32 b) { return a < b ? a : b; }
__device__ __forceinline__ u32 umax32(u32 a, u32 b) { return a > b ? a : b; }

__device__ __forceinline__ f16x8 cvt8(float4 a, float4 b) {
    f16x8 h;
    h[0] = (f16)a.x; h[1] = (f16)a.y; h[2] = (f16)a.z; h[3] = (f16)a.w;
    h[4] = (f16)b.x; h[5] = (f16)b.y; h[6] = (f16)b.z; h[7] = (f16)b.w;
    return h;
}

// ---------------------------------------------------------------------------
__global__ void zero_commit_kernel(float* p) { *p = 0.0f; }

// norms[row] = ||E||^2 exact; ascore[row] = 512 - 0.5*||E||^2 (keeps approx
// scores strictly positive so uint ordering of float bits is valid)
__global__ void norms_kernel(const float* __restrict__ cb, float* __restrict__ norms,
                             float* __restrict__ ascore) {
    int row = blockIdx.x;
    int lane = threadIdx.x;
    const float* r = cb + (size_t)row * DDIM;
    float2 v = *(const float2*)(r + lane * 2);
    float s = v.x * v.x + v.y * v.y;
    #pragma unroll
    for (int m = 32; m >= 1; m >>= 1) s += __shfl_xor(s, m);
    if (lane == 0) { norms[row] = s; ascore[row] = 512.0f - 0.5f * s; }
}

__global__ void preconv_kernel(const float* __restrict__ cb, f16* __restrict__ cb16) {
    size_t base = ((size_t)blockIdx.x * 256 + threadIdx.x) * 8;
    float4 a = *(const float4*)(cb + base);
    float4 b = *(const float4*)(cb + base + 4);
    *(f16x8*)(cb16 + base) = cvt8(a, b);
}

// ---------------------------------------------------------------------------
// Residual VQ: residual fp32 in registers; fp16 swizzled rh in LDS only for
// MFMA B-fragments; codebook A streamed from global fp16 (L2-resident);
// top-2 as packed u32 keys.
// amdgpu_waves_per_eu(4,8): round-6 evidence shows occupancy tracks the
// waves-per-eu hint, not resource limits ((256,2)->23% even at 18KB LDS /
// 104 VGPR). Budget for 4 waves/EU = 128 VGPR; current live set = 104 fits
// -> no spill (round-3 failure mode was the old ~150-reg live set at a
// 64-VGPR forced allocation).
template<bool PRE>
__global__ __launch_bounds__(BLOCKT)
__attribute__((amdgpu_waves_per_eu(4, 8)))
void rvq_kernel(const float* __restrict__ x, const float* __restrict__ cb,
                const f16* __restrict__ cb16, const float* __restrict__ W,
                const float* __restrict__ bias, const float* __restrict__ norms,
                const float* __restrict__ ascore, float* __restrict__ out) {
    __shared__ f16   rh[TM * DDIM];    // 16 KB residual/y fp16, swizzled
    __shared__ uint2 cand[4][TM];      // 2 KB  per-wave top2 keys per point

    const int tid  = threadIdx.x;
    const int wid  = tid >> 6;
    const int lane = tid & 63;
    const int g    = lane >> 4;      // k-group 0..3
    const int li   = lane & 15;      // row/col within 16-tile
    const int p_own = tid >> 2;      // owned point 0..63
    const int q     = tid & 3;       // owned d-quarter
    const int p0    = blockIdx.x * TM;

    // ---- x -> r (regs) and rh (fp16 LDS) ----
    float r[32];
    {
        const float* xs = x + (size_t)(p0 + p_own) * DDIM + q * 32;
        #pragma unroll
        for (int k = 0; k < 8; ++k) {
            float4 v = *(const float4*)(xs + 4 * k);
            r[4*k] = v.x; r[4*k+1] = v.y; r[4*k+2] = v.z; r[4*k+3] = v.w;
        }
    }
    #pragma unroll
    for (int k = 0; k < 4; ++k) {
        f16x8 h;
        #pragma unroll
        for (int m = 0; m < 8; ++m) h[m] = (f16)r[8*k+m];
        *(f16x8*)&rh[swz(p_own, q * 4 + k)] = h;
    }
    __syncthreads();

    float commit_part = 0.0f;

    #pragma unroll 1
    for (int s = 0; s < NVQ; ++s) {
        // ---- B fragments from rh (one b128 each), reused over all 512 codes ----
        f16x8 Bf[4][4];
        #pragma unroll
        for (int j = 0; j < 4; ++j)
            #pragma unroll
            for (int ks = 0; ks < 4; ++ks)
                Bf[j][ks] = *(const f16x8*)&rh[swz(16 * j + li, ks * 4 + g)];

        u32 k1[4], k2[4];
        #pragma unroll
        for (int j = 0; j < 4; ++j) { k1[j] = 0u; k2[j] = 0u; }

        const f16*   Ab   = cb16 + ((size_t)s * KCODES + 16 * wid + li) * DDIM + g * 8;
        const float* Ab32 = cb   + ((size_t)s * KCODES + 16 * wid + li) * DDIM + g * 8;
        const float* asb  = ascore + s * KCODES + 16 * wid + 4 * g;

        #pragma unroll 2
        for (int ch = 0; ch < 8; ++ch) {
            float4 as4 = *(const float4*)(asb + ch * 64);
            f32x4 acc[4];
            #pragma unroll
            for (int j = 0; j < 4; ++j) acc[j] = (f32x4)0.0f;

            #pragma unroll
            for (int ks = 0; ks < 4; ++ks) {
                f16x8 Af;
                if (PRE) {
                    Af = *(const f16x8*)(Ab + (size_t)ch * 64 * DDIM + ks * 32);
                } else {
                    const float* ap = Ab32 + (size_t)ch * 64 * DDIM + ks * 32;
                    Af = cvt8(*(const float4*)ap, *(const float4*)(ap + 4));
                }
                #pragma unroll
                for (int j = 0; j < 4; ++j)
                    acc[j] = __builtin_amdgcn_mfma_f32_16x16x32_f16(Af, Bf[j][ks], acc[j], 0, 0, 0);
            }

            const int invc = 511 - (ch * 64 + 16 * wid + 4 * g);
            #pragma unroll
            for (int j = 0; j < 4; ++j) {
                #pragma unroll
                for (int reg = 0; reg < 4; ++reg) {
                    float sc = acc[j][reg] +
                        ((reg == 0) ? as4.x : (reg == 1) ? as4.y : (reg == 2) ? as4.z : as4.w);
                    u32 key = (__float_as_uint(sc) & 0xFFFFFE00u) | (u32)(invc - reg);
                    u32 lo = umin32(k1[j], key);
                    k1[j] = umax32(k1[j], key);
                    k2[j] = umax32(k2[j], lo);
                }
            }
        }

        // ---- in-wave top-2 butterfly across k-groups (lanes xor 16, 32) ----
        #pragma unroll
        for (int m = 16; m <= 32; m <<= 1) {
            #pragma unroll
            for (int j = 0; j < 4; ++j) {
                u32 o1 = (u32)__shfl_xor((int)k1[j], m);
                u32 o2 = (u32)__shfl_xor((int)k2[j], m);
                u32 lo = umin32(k1[j], o1);
                k1[j] = umax32(k1[j], o1);
                k2[j] = umax32(umax32(k2[j], o2), lo);
            }
        }
        if (lane < 16) {
            #pragma unroll
            for (int j = 0; j < 4; ++j)
                cand[wid][16 * j + li] = make_uint2(k1[j], k2[j]);
        }
        __syncthreads();

        // ---- cross-wave merge, redundantly in every thread ----
        uint2 v0 = cand[0][p_own];
        u32 m1 = v0.x, m2 = v0.y;
        #pragma unroll
        for (int w = 1; w < 4; ++w) {
            uint2 vv = cand[w][p_own];
            u32 lo = umin32(m1, vv.x);
            m1 = umax32(m1, vv.x);
            m2 = umax32(umax32(m2, vv.y), lo);
        }
        int c1 = 511 - (int)(m1 & 0x1FFu);
        int c2 = 511 - (int)(m2 & 0x1FFu);

        // ---- exact fp32 rescue on top-2 (registers only) ----
        const float* E1 = cb + (size_t)(s * KCODES + c1) * DDIM + q * 32;
        const float* E2 = cb + (size_t)(s * KCODES + c2) * DDIM + q * 32;
        float dot1 = 0.0f, dot2 = 0.0f;
        #pragma unroll
        for (int k = 0; k < 8; ++k) {
            float4 a = *(const float4*)(E1 + 4 * k);
            dot1 += a.x * r[4*k] + a.y * r[4*k+1] + a.z * r[4*k+2] + a.w * r[4*k+3];
        }
        #pragma unroll
        for (int k = 0; k < 8; ++k) {
            float4 a = *(const float4*)(E2 + 4 * k);
            dot2 += a.x * r[4*k] + a.y * r[4*k+1] + a.z * r[4*k+2] + a.w * r[4*k+3];
        }
        dot1 += __shfl_xor(dot1, 1); dot1 += __shfl_xor(dot1, 2);
        dot2 += __shfl_xor(dot2, 1); dot2 += __shfl_xor(dot2, 2);
        float d1e = fmaf(-2.0f, dot1, norms[s * KCODES + c1]);
        float d2e = fmaf(-2.0f, dot2, norms[s * KCODES + c2]);
        int best = (d2e < d1e || (d2e == d1e && c2 < c1)) ? c2 : c1;

        if (s == 0 && q == 0)
            out[(size_t)NPTS * DDIM + p0 + p_own] = (float)best;

        // ---- exact residual update (regs) + rh rewrite for next stage ----
        {
            const float* Eb = cb + (size_t)(s * KCODES + best) * DDIM + q * 32;
            float cp = 0.0f;
            #pragma unroll
            for (int k = 0; k < 8; ++k) {
                float4 e = *(const float4*)(Eb + 4 * k);
                r[4*k]   -= e.x; r[4*k+1] -= e.y; r[4*k+2] -= e.z; r[4*k+3] -= e.w;
                cp += r[4*k]*r[4*k] + r[4*k+1]*r[4*k+1] + r[4*k+2]*r[4*k+2] + r[4*k+3]*r[4*k+3];
            }
            if (s == 0) commit_part = cp;
        }
        if (s < NVQ - 1) {
            #pragma unroll
            for (int k = 0; k < 4; ++k) {
                f16x8 h;
                #pragma unroll
                for (int m = 0; m < 8; ++m) h[m] = (f16)r[8*k+m];
                *(f16x8*)&rh[swz(p_own, q * 4 + k)] = h;
            }
        }
        __syncthreads();
    }

    // ---- y = x - r_final -> rh ----
    {
        const float* xs = x + (size_t)(p0 + p_own) * DDIM + q * 32;
        #pragma unroll
        for (int k = 0; k < 4; ++k) {
            float4 a = *(const float4*)(xs + 8 * k);
            float4 b = *(const float4*)(xs + 8 * k + 4);
            f16x8 h;
            h[0]=(f16)(a.x - r[8*k+0]); h[1]=(f16)(a.y - r[8*k+1]);
            h[2]=(f16)(a.z - r[8*k+2]); h[3]=(f16)(a.w - r[8*k+3]);
            h[4]=(f16)(b.x - r[8*k+4]); h[5]=(f16)(b.y - r[8*k+5]);
            h[6]=(f16)(b.z - r[8*k+6]); h[7]=(f16)(b.w - r[8*k+7]);
            *(f16x8*)&rh[swz(p_own, q * 4 + k)] = h;
        }
    }
    __syncthreads();

    // ---- final linear: out = y @ W^T + b (W rows streamed from global) ----
    {
        f16x8 Yf[4][4];
        #pragma unroll
        for (int j = 0; j < 4; ++j)
            #pragma unroll
            for (int ks = 0; ks < 4; ++ks)
                Yf[j][ks] = *(const f16x8*)&rh[swz(16 * j + li, ks * 4 + g)];

        #pragma unroll 1
        for (int ch = 0; ch < 2; ++ch) {
            float4 b4 = *(const float4*)(bias + ch * 64 + 16 * wid + 4 * g);
            f32x4 acc[4];
            #pragma unroll
            for (int j = 0; j < 4; ++j) {
                acc[j][0] = b4.x; acc[j][1] = b4.y; acc[j][2] = b4.z; acc[j][3] = b4.w;
            }
            #pragma unroll
            for (int ks = 0; ks < 4; ++ks) {
                const float* wp = W + (size_t)(ch * 64 + 16 * wid + li) * DDIM + ks * 32 + g * 8;
                f16x8 Af = cvt8(*(const float4*)wp, *(const float4*)(wp + 4));
                #pragma unroll
                for (int j = 0; j < 4; ++j)
                    acc[j] = __builtin_amdgcn_mfma_f32_16x16x32_f16(Af, Yf[j][ks], acc[j], 0, 0, 0);
            }
            int obase = ch * 64 + 16 * wid + 4 * g;
            #pragma unroll
            for (int j = 0; j < 4; ++j)
                *(float4*)(out + (size_t)(p0 + 16 * j + li) * DDIM + obase) =
                    make_float4(acc[j][0], acc[j][1], acc[j][2], acc[j][3]);
        }
    }

    // ---- commit loss: wave shuffle-reduce + block atomic ----
    {
        float cp = commit_part;
        #pragma unroll
        for (int m = 1; m <= 32; m <<= 1) cp += __shfl_xor(cp, m);
        __syncthreads();
        float* wsum = (float*)cand;
        if (lane == 0) wsum[wid] = cp;
        __syncthreads();
        if (tid == 0) {
            float t = (wsum[0] + wsum[1]) + (wsum[2] + wsum[3]);
            atomicAdd(out + (size_t)NPTS * DDIM + NPTS,
                      t * (1.0f / ((float)NPTS * (float)DDIM)));
        }
    }
}

// ---------------------------------------------------------------------------
extern "C" void kernel_launch(void* const* d_in, const int* in_sizes, int n_in,
                              void* d_out, int out_size, void* d_ws, size_t ws_size,
                              hipStream_t stream) {
    const float* x    = (const float*)d_in[0];
    const float* cb   = (const float*)d_in[1];
    const float* linw = (const float*)d_in[2];
    const float* linb = (const float*)d_in[3];
    float* out    = (float*)d_out;
    float* norms  = (float*)d_ws;                        // 3072 f
    float* ascore = norms + 4096;                        // 3072 f
    f16*   cb16   = (f16*)((char*)d_ws + 32768);         // 786432 B
    const size_t need = 32768 + (size_t)NVQ * KCODES * DDIM * 2;

    zero_commit_kernel<<<1, 1, 0, stream>>>(out + (size_t)NPTS * DDIM + NPTS);
    norms_kernel<<<NVQ * KCODES, 64, 0, stream>>>(cb, norms, ascore);

    if (ws_size >= need) {
        preconv_kernel<<<(NVQ * KCODES * DDIM) / (256 * 8), 256, 0, stream>>>(cb, cb16);
        rvq_kernel<true><<<NPTS / TM, BLOCKT, 0, stream>>>(x, cb, cb16, linw, linb,
                                                           norms, ascore, out);
    } else {
        rvq_kernel<false><<<NPTS / TM, BLOCKT, 0, stream>>>(x, cb, cb16, linw, linb,
                                                            norms, ascore, out);
    }
}

// Round 10
// 800.759 us; speedup vs baseline: 1.1691x; 1.1691x over previous
//
#include <hip/hip_runtime.h>
#include <float.h>

typedef _Float16 f16;
typedef f16 f16x8 __attribute__((ext_vector_type(8)));
typedef float f32x4 __attribute__((ext_vector_type(4)));
typedef unsigned int u32;

#define NPTS 262144
#define DDIM 128
#define NVQ 6
#define KCODES 512
#define TM 64
#define BLOCKT 256

__device__ __forceinline__ int swz(int row, int grp) {
    return row * DDIM + ((grp ^ (row & 7)) << 3);
}
__device__ __forceinline__ u32 umin32(u32 a, u32 b) { return a < b ? a : b; }
__device__ __forceinline__ u32 umax32(u32 a, u32 b) { return a > b ? a : b; }

__device__ __forceinline__ f16x8 cvt8(float4 a, float4 b) {
    f16x8 h;
    h[0] = (f16)a.x; h[1] = (f16)a.y; h[2] = (f16)a.z; h[3] = (f16)a.w;
    h[4] = (f16)b.x; h[5] = (f16)b.y; h[6] = (f16)b.z; h[7] = (f16)b.w;
    return h;
}

// ---------------------------------------------------------------------------
__global__ void zero_commit_kernel(float* p) { *p = 0.0f; }

// norms[row] = ||E||^2 exact; ascore[row] = 512 - 0.5*||E||^2 (keeps approx
// scores strictly positive so uint ordering of float bits is valid)
__global__ void norms_kernel(const float* __restrict__ cb, float* __restrict__ norms,
                             float* __restrict__ ascore) {
    int row = blockIdx.x;
    int lane = threadIdx.x;
    const float* r = cb + (size_t)row * DDIM;
    float2 v = *(const float2*)(r + lane * 2);
    float s = v.x * v.x + v.y * v.y;
    #pragma unroll
    for (int m = 32; m >= 1; m >>= 1) s += __shfl_xor(s, m);
    if (lane == 0) { norms[row] = s; ascore[row] = 512.0f - 0.5f * s; }
}

__global__ void preconv_kernel(const float* __restrict__ cb, f16* __restrict__ cb16) {
    size_t base = ((size_t)blockIdx.x * 256 + threadIdx.x) * 8;
    float4 a = *(const float4*)(cb + base);
    float4 b = *(const float4*)(cb + base + 4);
    *(f16x8*)(cb16 + base) = cvt8(a, b);
}

// ---------------------------------------------------------------------------
// Residual VQ — round-6 body (PASSING, absmax 5.421875) + two numerics-
// invariant levers:
//  (a) amdgpu_waves_per_eu(3,3): reg budget 512/3=170 > round-6 natural
//      total (~104 arch + AGPR) -> no spill, 3 waves/SIMD (r7 proved the
//      attribute itself preserves correctness; r7's spill came from a 64-reg
//      budget, not the attribute).
//  (b) depth-1 rotating prefetch of the A-stream (Afn): chunk ch+1's loads
//      issue before chunk ch's MFMAs. acc[j] still sums ks=0,1,2,3 with
//      identical values -> FP ORDER FROZEN (round-8 lesson: any reorder
//      flips near-tie selections and breaks the absmax contract).
// The laundered-LDS Bf path (r8/r9) is retired: two unexplained correctness
// failures; Bf stays a register cache.
template<bool PRE>
__global__ __launch_bounds__(BLOCKT)
__attribute__((amdgpu_waves_per_eu(3, 3)))
void rvq_kernel(const float* __restrict__ x, const float* __restrict__ cb,
                const f16* __restrict__ cb16, const float* __restrict__ W,
                const float* __restrict__ bias, const float* __restrict__ norms,
                const float* __restrict__ ascore, float* __restrict__ out) {
    __shared__ f16   rh[TM * DDIM];    // 16 KB residual/y fp16, swizzled
    __shared__ uint2 cand[4][TM];      // 2 KB  per-wave top2 keys per point

    const int tid  = threadIdx.x;
    const int wid  = tid >> 6;
    const int lane = tid & 63;
    const int g    = lane >> 4;      // k-group 0..3
    const int li   = lane & 15;      // row/col within 16-tile
    const int p_own = tid >> 2;      // owned point 0..63
    const int q     = tid & 3;       // owned d-quarter
    const int p0    = blockIdx.x * TM;

    // ---- x -> r (regs) and rh (fp16 LDS) ----
    float r[32];
    {
        const float* xs = x + (size_t)(p0 + p_own) * DDIM + q * 32;
        #pragma unroll
        for (int k = 0; k < 8; ++k) {
            float4 v = *(const float4*)(xs + 4 * k);
            r[4*k] = v.x; r[4*k+1] = v.y; r[4*k+2] = v.z; r[4*k+3] = v.w;
        }
    }
    #pragma unroll
    for (int k = 0; k < 4; ++k) {
        f16x8 h;
        #pragma unroll
        for (int m = 0; m < 8; ++m) h[m] = (f16)r[8*k+m];
        *(f16x8*)&rh[swz(p_own, q * 4 + k)] = h;
    }
    __syncthreads();

    float commit_part = 0.0f;

    #pragma unroll 1
    for (int s = 0; s < NVQ; ++s) {
        // ---- B fragments from rh (one b128 each), reused over all 512 codes ----
        f16x8 Bf[4][4];
        #pragma unroll
        for (int j = 0; j < 4; ++j)
            #pragma unroll
            for (int ks = 0; ks < 4; ++ks)
                Bf[j][ks] = *(const f16x8*)&rh[swz(16 * j + li, ks * 4 + g)];

        u32 k1[4], k2[4];
        #pragma unroll
        for (int j = 0; j < 4; ++j) { k1[j] = 0u; k2[j] = 0u; }

        const f16*   Ab   = cb16 + ((size_t)s * KCODES + 16 * wid + li) * DDIM + g * 8;
        const float* Ab32 = cb   + ((size_t)s * KCODES + 16 * wid + li) * DDIM + g * 8;
        const float* asb  = ascore + s * KCODES + 16 * wid + 4 * g;

        // ---- prefetch chunk 0's A fragments ----
        f16x8 Afn[4];
        #pragma unroll
        for (int ks = 0; ks < 4; ++ks) {
            if (PRE) {
                Afn[ks] = *(const f16x8*)(Ab + ks * 32);
            } else {
                const float* ap = Ab32 + ks * 32;
                Afn[ks] = cvt8(*(const float4*)ap, *(const float4*)(ap + 4));
            }
        }

        #pragma unroll 1
        for (int ch = 0; ch < 8; ++ch) {
            float4 as4 = *(const float4*)(asb + ch * 64);
            // rotate: current <- prefetched; issue next chunk's loads now,
            // MFMAs below don't depend on them -> loads hide under compute.
            f16x8 Afc[4];
            #pragma unroll
            for (int ks = 0; ks < 4; ++ks) Afc[ks] = Afn[ks];
            if (ch < 7) {
                #pragma unroll
                for (int ks = 0; ks < 4; ++ks) {
                    if (PRE) {
                        Afn[ks] = *(const f16x8*)(Ab + (size_t)(ch + 1) * 64 * DDIM + ks * 32);
                    } else {
                        const float* ap = Ab32 + (size_t)(ch + 1) * 64 * DDIM + ks * 32;
                        Afn[ks] = cvt8(*(const float4*)ap, *(const float4*)(ap + 4));
                    }
                }
            }

            f32x4 acc[4];
            #pragma unroll
            for (int j = 0; j < 4; ++j) acc[j] = (f32x4)0.0f;

            // FP order frozen: each acc[j] accumulates ks = 0,1,2,3.
            #pragma unroll
            for (int ks = 0; ks < 4; ++ks) {
                #pragma unroll
                for (int j = 0; j < 4; ++j)
                    acc[j] = __builtin_amdgcn_mfma_f32_16x16x32_f16(Afc[ks], Bf[j][ks], acc[j], 0, 0, 0);
            }

            const int invc = 511 - (ch * 64 + 16 * wid + 4 * g);
            #pragma unroll
            for (int j = 0; j < 4; ++j) {
                #pragma unroll
                for (int reg = 0; reg < 4; ++reg) {
                    float sc = acc[j][reg] +
                        ((reg == 0) ? as4.x : (reg == 1) ? as4.y : (reg == 2) ? as4.z : as4.w);
                    u32 key = (__float_as_uint(sc) & 0xFFFFFE00u) | (u32)(invc - reg);
                    u32 lo = umin32(k1[j], key);
                    k1[j] = umax32(k1[j], key);
                    k2[j] = umax32(k2[j], lo);
                }
            }
        }

        // ---- in-wave top-2 butterfly across k-groups (lanes xor 16, 32) ----
        #pragma unroll
        for (int m = 16; m <= 32; m <<= 1) {
            #pragma unroll
            for (int j = 0; j < 4; ++j) {
                u32 o1 = (u32)__shfl_xor((int)k1[j], m);
                u32 o2 = (u32)__shfl_xor((int)k2[j], m);
                u32 lo = umin32(k1[j], o1);
                k1[j] = umax32(k1[j], o1);
                k2[j] = umax32(umax32(k2[j], o2), lo);
            }
        }
        if (lane < 16) {
            #pragma unroll
            for (int j = 0; j < 4; ++j)
                cand[wid][16 * j + li] = make_uint2(k1[j], k2[j]);
        }
        __syncthreads();   // also: all waves done reading rh for this stage

        // ---- cross-wave merge, redundantly in every thread ----
        uint2 v0 = cand[0][p_own];
        u32 m1 = v0.x, m2 = v0.y;
        #pragma unroll
        for (int w = 1; w < 4; ++w) {
            uint2 vv = cand[w][p_own];
            u32 lo = umin32(m1, vv.x);
            m1 = umax32(m1, vv.x);
            m2 = umax32(umax32(m2, vv.y), lo);
        }
        int c1 = 511 - (int)(m1 & 0x1FFu);
        int c2 = 511 - (int)(m2 & 0x1FFu);

        // ---- exact fp32 rescue on top-2 (registers only) ----
        const float* E1 = cb + (size_t)(s * KCODES + c1) * DDIM + q * 32;
        const float* E2 = cb + (size_t)(s * KCODES + c2) * DDIM + q * 32;
        float dot1 = 0.0f, dot2 = 0.0f;
        #pragma unroll
        for (int k = 0; k < 8; ++k) {
            float4 a = *(const float4*)(E1 + 4 * k);
            dot1 += a.x * r[4*k] + a.y * r[4*k+1] + a.z * r[4*k+2] + a.w * r[4*k+3];
        }
        #pragma unroll
        for (int k = 0; k < 8; ++k) {
            float4 a = *(const float4*)(E2 + 4 * k);
            dot2 += a.x * r[4*k] + a.y * r[4*k+1] + a.z * r[4*k+2] + a.w * r[4*k+3];
        }
        dot1 += __shfl_xor(dot1, 1); dot1 += __shfl_xor(dot1, 2);
        dot2 += __shfl_xor(dot2, 1); dot2 += __shfl_xor(dot2, 2);
        float d1e = fmaf(-2.0f, dot1, norms[s * KCODES + c1]);
        float d2e = fmaf(-2.0f, dot2, norms[s * KCODES + c2]);
        int best = (d2e < d1e || (d2e == d1e && c2 < c1)) ? c2 : c1;

        if (s == 0 && q == 0)
            out[(size_t)NPTS * DDIM + p0 + p_own] = (float)best;

        // ---- exact residual update (regs) + rh rewrite for next stage ----
        {
            const float* Eb = cb + (size_t)(s * KCODES + best) * DDIM + q * 32;
            float cp = 0.0f;
            #pragma unroll
            for (int k = 0; k < 8; ++k) {
                float4 e = *(const float4*)(Eb + 4 * k);
                r[4*k]   -= e.x; r[4*k+1] -= e.y; r[4*k+2] -= e.z; r[4*k+3] -= e.w;
                cp += r[4*k]*r[4*k] + r[4*k+1]*r[4*k+1] + r[4*k+2]*r[4*k+2] + r[4*k+3]*r[4*k+3];
            }
            if (s == 0) commit_part = cp;
        }
        if (s < NVQ - 1) {
            #pragma unroll
            for (int k = 0; k < 4; ++k) {
                f16x8 h;
                #pragma unroll
                for (int m = 0; m < 8; ++m) h[m] = (f16)r[8*k+m];
                *(f16x8*)&rh[swz(p_own, q * 4 + k)] = h;
            }
        }
        __syncthreads();
    }

    // ---- y = x - r_final -> rh ----
    {
        const float* xs = x + (size_t)(p0 + p_own) * DDIM + q * 32;
        #pragma unroll
        for (int k = 0; k < 4; ++k) {
            float4 a = *(const float4*)(xs + 8 * k);
            float4 b = *(const float4*)(xs + 8 * k + 4);
            f16x8 h;
            h[0]=(f16)(a.x - r[8*k+0]); h[1]=(f16)(a.y - r[8*k+1]);
            h[2]=(f16)(a.z - r[8*k+2]); h[3]=(f16)(a.w - r[8*k+3]);
            h[4]=(f16)(b.x - r[8*k+4]); h[5]=(f16)(b.y - r[8*k+5]);
            h[6]=(f16)(b.z - r[8*k+6]); h[7]=(f16)(b.w - r[8*k+7]);
            *(f16x8*)&rh[swz(p_own, q * 4 + k)] = h;
        }
    }
    __syncthreads();

    // ---- final linear: out = y @ W^T + b (W rows streamed from global) ----
    {
        f16x8 Yf[4][4];
        #pragma unroll
        for (int j = 0; j < 4; ++j)
            #pragma unroll
            for (int ks = 0; ks < 4; ++ks)
                Yf[j][ks] = *(const f16x8*)&rh[swz(16 * j + li, ks * 4 + g)];

        #pragma unroll 1
        for (int ch = 0; ch < 2; ++ch) {
            float4 b4 = *(const float4*)(bias + ch * 64 + 16 * wid + 4 * g);
            f32x4 acc[4];
            #pragma unroll
            for (int j = 0; j < 4; ++j) {
                acc[j][0] = b4.x; acc[j][1] = b4.y; acc[j][2] = b4.z; acc[j][3] = b4.w;
            }
            #pragma unroll
            for (int ks = 0; ks < 4; ++ks) {
                const float* wp = W + (size_t)(ch * 64 + 16 * wid + li) * DDIM + ks * 32 + g * 8;
                f16x8 Af = cvt8(*(const float4*)wp, *(const float4*)(wp + 4));
                #pragma unroll
                for (int j = 0; j < 4; ++j)
                    acc[j] = __builtin_amdgcn_mfma_f32_16x16x32_f16(Af, Yf[j][ks], acc[j], 0, 0, 0);
            }
            int obase = ch * 64 + 16 * wid + 4 * g;
            #pragma unroll
            for (int j = 0; j < 4; ++j)
                *(float4*)(out + (size_t)(p0 + 16 * j + li) * DDIM + obase) =
                    make_float4(acc[j][0], acc[j][1], acc[j][2], acc[j][3]);
        }
    }

    // ---- commit loss: wave shuffle-reduce + block atomic ----
    {
        float cp = commit_part;
        #pragma unroll
        for (int m = 1; m <= 32; m <<= 1) cp += __shfl_xor(cp, m);
        __syncthreads();
        float* wsum = (float*)cand;
        if (lane == 0) wsum[wid] = cp;
        __syncthreads();
        if (tid == 0) {
            float t = (wsum[0] + wsum[1]) + (wsum[2] + wsum[3]);
            atomicAdd(out + (size_t)NPTS * DDIM + NPTS,
                      t * (1.0f / ((float)NPTS * (float)DDIM)));
        }
    }
}

// ---------------------------------------------------------------------------
extern "C" void kernel_launch(void* const* d_in, const int* in_sizes, int n_in,
                              void* d_out, int out_size, void* d_ws, size_t ws_size,
                              hipStream_t stream) {
    const float* x    = (const float*)d_in[0];
    const float* cb   = (const float*)d_in[1];
    const float* linw = (const float*)d_in[2];
    const float* linb = (const float*)d_in[3];
    float* out    = (float*)d_out;
    float* norms  = (float*)d_ws;                        // 3072 f
    float* ascore = norms + 4096;                        // 3072 f
    f16*   cb16   = (f16*)((char*)d_ws + 32768);         // 786432 B
    const size_t need = 32768 + (size_t)NVQ * KCODES * DDIM * 2;

    zero_commit_kernel<<<1, 1, 0, stream>>>(out + (size_t)NPTS * DDIM + NPTS);
    norms_kernel<<<NVQ * KCODES, 64, 0, stream>>>(cb, norms, ascore);

    if (ws_size >= need) {
        preconv_kernel<<<(NVQ * KCODES * DDIM) / (256 * 8), 256, 0, stream>>>(cb, cb16);
        rvq_kernel<true><<<NPTS / TM, BLOCKT, 0, stream>>>(x, cb, cb16, linw, linb,
                                                           norms, ascore, out);
    } else {
        rvq_kernel<false><<<NPTS / TM, BLOCKT, 0, stream>>>(x, cb, cb16, linw, linb,
                                                            norms, ascore, out);
    }
}

// Round 11
// 744.081 us; speedup vs baseline: 1.2582x; 1.0762x over previous
//
#include <hip/hip_runtime.h>
#include <float.h>

typedef _Float16 f16;
typedef f16 f16x8 __attribute__((ext_vector_type(8)));
typedef float f32x4 __attribute__((ext_vector_type(4)));
typedef unsigned int u32;

#define NPTS 262144
#define DDIM 128
#define NVQ 6
#define KCODES 512
#define TM 64
#define BLOCKT 256

__device__ __forceinline__ int swz(int row, int grp) {
    return row * DDIM + ((grp ^ (row & 7)) << 3);
}
__device__ __forceinline__ u32 umin32(u32 a, u32 b) { return a < b ? a : b; }
__device__ __forceinline__ u32 umax32(u32 a, u32 b) { return a > b ? a : b; }

__device__ __forceinline__ f16x8 cvt8(float4 a, float4 b) {
    f16x8 h;
    h[0] = (f16)a.x; h[1] = (f16)a.y; h[2] = (f16)a.z; h[3] = (f16)a.w;
    h[4] = (f16)b.x; h[5] = (f16)b.y; h[6] = (f16)b.z; h[7] = (f16)b.w;
    return h;
}

// ---------------------------------------------------------------------------
__global__ void zero_commit_kernel(float* p) { *p = 0.0f; }

// norms[row] = ||E||^2 exact; ascore[row] = 512 - 0.5*||E||^2 (keeps approx
// scores strictly positive so uint ordering of float bits is valid)
__global__ void norms_kernel(const float* __restrict__ cb, float* __restrict__ norms,
                             float* __restrict__ ascore) {
    int row = blockIdx.x;
    int lane = threadIdx.x;
    const float* r = cb + (size_t)row * DDIM;
    float2 v = *(const float2*)(r + lane * 2);
    float s = v.x * v.x + v.y * v.y;
    #pragma unroll
    for (int m = 32; m >= 1; m >>= 1) s += __shfl_xor(s, m);
    if (lane == 0) { norms[row] = s; ascore[row] = 512.0f - 0.5f * s; }
}

__global__ void preconv_kernel(const float* __restrict__ cb, f16* __restrict__ cb16) {
    size_t base = ((size_t)blockIdx.x * 256 + threadIdx.x) * 8;
    float4 a = *(const float4*)(cb + base);
    float4 b = *(const float4*)(cb + base + 4);
    *(f16x8*)(cb16 + base) = cvt8(a, b);
}

// ---------------------------------------------------------------------------
// Residual VQ — round-6 body EXACTLY (PASSING, absmax 5.421875, no spill)
// with two numerics-neutral deltas:
//  (a) amdgpu_waves_per_eu(3,3): budget 512/3=170 > r6 live set (~120 total)
//      -> 3 waves/SIMD, no spill. (r10's spill came from the Afn prefetch's
//      +30 live regs, not the attribute — prefetch removed.)
//  (b) s_setprio(1) around the MFMA cluster: resident blocks are independent
//      and desynced -> scheduler favors MFMA-issuing waves (T5 regime).
// FP ORDER FROZEN: ks=0,1,2,3 per acc[j]; ascore added after. (r8/r9: any
// reorder flips near-tie selections and breaks the absmax contract.)
template<bool PRE>
__global__ __launch_bounds__(BLOCKT)
__attribute__((amdgpu_waves_per_eu(3, 3)))
void rvq_kernel(const float* __restrict__ x, const float* __restrict__ cb,
                const f16* __restrict__ cb16, const float* __restrict__ W,
                const float* __restrict__ bias, const float* __restrict__ norms,
                const float* __restrict__ ascore, float* __restrict__ out) {
    __shared__ f16   rh[TM * DDIM];    // 16 KB residual/y fp16, swizzled
    __shared__ uint2 cand[4][TM];      // 2 KB  per-wave top2 keys per point

    const int tid  = threadIdx.x;
    const int wid  = tid >> 6;
    const int lane = tid & 63;
    const int g    = lane >> 4;      // k-group 0..3
    const int li   = lane & 15;      // row/col within 16-tile
    const int p_own = tid >> 2;      // owned point 0..63
    const int q     = tid & 3;       // owned d-quarter
    const int p0    = blockIdx.x * TM;

    // ---- x -> r (regs) and rh (fp16 LDS) ----
    float r[32];
    {
        const float* xs = x + (size_t)(p0 + p_own) * DDIM + q * 32;
        #pragma unroll
        for (int k = 0; k < 8; ++k) {
            float4 v = *(const float4*)(xs + 4 * k);
            r[4*k] = v.x; r[4*k+1] = v.y; r[4*k+2] = v.z; r[4*k+3] = v.w;
        }
    }
    #pragma unroll
    for (int k = 0; k < 4; ++k) {
        f16x8 h;
        #pragma unroll
        for (int m = 0; m < 8; ++m) h[m] = (f16)r[8*k+m];
        *(f16x8*)&rh[swz(p_own, q * 4 + k)] = h;
    }
    __syncthreads();

    float commit_part = 0.0f;

    #pragma unroll 1
    for (int s = 0; s < NVQ; ++s) {
        // ---- B fragments from rh (one b128 each), reused over all 512 codes ----
        f16x8 Bf[4][4];
        #pragma unroll
        for (int j = 0; j < 4; ++j)
            #pragma unroll
            for (int ks = 0; ks < 4; ++ks)
                Bf[j][ks] = *(const f16x8*)&rh[swz(16 * j + li, ks * 4 + g)];

        u32 k1[4], k2[4];
        #pragma unroll
        for (int j = 0; j < 4; ++j) { k1[j] = 0u; k2[j] = 0u; }

        const f16*   Ab   = cb16 + ((size_t)s * KCODES + 16 * wid + li) * DDIM + g * 8;
        const float* Ab32 = cb   + ((size_t)s * KCODES + 16 * wid + li) * DDIM + g * 8;
        const float* asb  = ascore + s * KCODES + 16 * wid + 4 * g;

        #pragma unroll 2
        for (int ch = 0; ch < 8; ++ch) {
            float4 as4 = *(const float4*)(asb + ch * 64);
            f32x4 acc[4];
            #pragma unroll
            for (int j = 0; j < 4; ++j) acc[j] = (f32x4)0.0f;

            __builtin_amdgcn_s_setprio(1);
            #pragma unroll
            for (int ks = 0; ks < 4; ++ks) {
                f16x8 Af;
                if (PRE) {
                    Af = *(const f16x8*)(Ab + (size_t)ch * 64 * DDIM + ks * 32);
                } else {
                    const float* ap = Ab32 + (size_t)ch * 64 * DDIM + ks * 32;
                    Af = cvt8(*(const float4*)ap, *(const float4*)(ap + 4));
                }
                #pragma unroll
                for (int j = 0; j < 4; ++j)
                    acc[j] = __builtin_amdgcn_mfma_f32_16x16x32_f16(Af, Bf[j][ks], acc[j], 0, 0, 0);
            }
            __builtin_amdgcn_s_setprio(0);

            const int invc = 511 - (ch * 64 + 16 * wid + 4 * g);
            #pragma unroll
            for (int j = 0; j < 4; ++j) {
                #pragma unroll
                for (int reg = 0; reg < 4; ++reg) {
                    float sc = acc[j][reg] +
                        ((reg == 0) ? as4.x : (reg == 1) ? as4.y : (reg == 2) ? as4.z : as4.w);
                    u32 key = (__float_as_uint(sc) & 0xFFFFFE00u) | (u32)(invc - reg);
                    u32 lo = umin32(k1[j], key);
                    k1[j] = umax32(k1[j], key);
                    k2[j] = umax32(k2[j], lo);
                }
            }
        }

        // ---- in-wave top-2 butterfly across k-groups (lanes xor 16, 32) ----
        #pragma unroll
        for (int m = 16; m <= 32; m <<= 1) {
            #pragma unroll
            for (int j = 0; j < 4; ++j) {
                u32 o1 = (u32)__shfl_xor((int)k1[j], m);
                u32 o2 = (u32)__shfl_xor((int)k2[j], m);
                u32 lo = umin32(k1[j], o1);
                k1[j] = umax32(k1[j], o1);
                k2[j] = umax32(umax32(k2[j], o2), lo);
            }
        }
        if (lane < 16) {
            #pragma unroll
            for (int j = 0; j < 4; ++j)
                cand[wid][16 * j + li] = make_uint2(k1[j], k2[j]);
        }
        __syncthreads();   // also: all waves done reading rh for this stage

        // ---- cross-wave merge, redundantly in every thread ----
        uint2 v0 = cand[0][p_own];
        u32 m1 = v0.x, m2 = v0.y;
        #pragma unroll
        for (int w = 1; w < 4; ++w) {
            uint2 vv = cand[w][p_own];
            u32 lo = umin32(m1, vv.x);
            m1 = umax32(m1, vv.x);
            m2 = umax32(umax32(m2, vv.y), lo);
        }
        int c1 = 511 - (int)(m1 & 0x1FFu);
        int c2 = 511 - (int)(m2 & 0x1FFu);

        // ---- exact fp32 rescue on top-2 (registers only) ----
        const float* E1 = cb + (size_t)(s * KCODES + c1) * DDIM + q * 32;
        const float* E2 = cb + (size_t)(s * KCODES + c2) * DDIM + q * 32;
        float dot1 = 0.0f, dot2 = 0.0f;
        #pragma unroll
        for (int k = 0; k < 8; ++k) {
            float4 a = *(const float4*)(E1 + 4 * k);
            dot1 += a.x * r[4*k] + a.y * r[4*k+1] + a.z * r[4*k+2] + a.w * r[4*k+3];
        }
        #pragma unroll
        for (int k = 0; k < 8; ++k) {
            float4 a = *(const float4*)(E2 + 4 * k);
            dot2 += a.x * r[4*k] + a.y * r[4*k+1] + a.z * r[4*k+2] + a.w * r[4*k+3];
        }
        dot1 += __shfl_xor(dot1, 1); dot1 += __shfl_xor(dot1, 2);
        dot2 += __shfl_xor(dot2, 1); dot2 += __shfl_xor(dot2, 2);
        float d1e = fmaf(-2.0f, dot1, norms[s * KCODES + c1]);
        float d2e = fmaf(-2.0f, dot2, norms[s * KCODES + c2]);
        int best = (d2e < d1e || (d2e == d1e && c2 < c1)) ? c2 : c1;

        if (s == 0 && q == 0)
            out[(size_t)NPTS * DDIM + p0 + p_own] = (float)best;

        // ---- exact residual update (regs) + rh rewrite for next stage ----
        {
            const float* Eb = cb + (size_t)(s * KCODES + best) * DDIM + q * 32;
            float cp = 0.0f;
            #pragma unroll
            for (int k = 0; k < 8; ++k) {
                float4 e = *(const float4*)(Eb + 4 * k);
                r[4*k]   -= e.x; r[4*k+1] -= e.y; r[4*k+2] -= e.z; r[4*k+3] -= e.w;
                cp += r[4*k]*r[4*k] + r[4*k+1]*r[4*k+1] + r[4*k+2]*r[4*k+2] + r[4*k+3]*r[4*k+3];
            }
            if (s == 0) commit_part = cp;
        }
        if (s < NVQ - 1) {
            #pragma unroll
            for (int k = 0; k < 4; ++k) {
                f16x8 h;
                #pragma unroll
                for (int m = 0; m < 8; ++m) h[m] = (f16)r[8*k+m];
                *(f16x8*)&rh[swz(p_own, q * 4 + k)] = h;
            }
        }
        __syncthreads();
    }

    // ---- y = x - r_final -> rh ----
    {
        const float* xs = x + (size_t)(p0 + p_own) * DDIM + q * 32;
        #pragma unroll
        for (int k = 0; k < 4; ++k) {
            float4 a = *(const float4*)(xs + 8 * k);
            float4 b = *(const float4*)(xs + 8 * k + 4);
            f16x8 h;
            h[0]=(f16)(a.x - r[8*k+0]); h[1]=(f16)(a.y - r[8*k+1]);
            h[2]=(f16)(a.z - r[8*k+2]); h[3]=(f16)(a.w - r[8*k+3]);
            h[4]=(f16)(b.x - r[8*k+4]); h[5]=(f16)(b.y - r[8*k+5]);
            h[6]=(f16)(b.z - r[8*k+6]); h[7]=(f16)(b.w - r[8*k+7]);
            *(f16x8*)&rh[swz(p_own, q * 4 + k)] = h;
        }
    }
    __syncthreads();

    // ---- final linear: out = y @ W^T + b (W rows streamed from global) ----
    {
        f16x8 Yf[4][4];
        #pragma unroll
        for (int j = 0; j < 4; ++j)
            #pragma unroll
            for (int ks = 0; ks < 4; ++ks)
                Yf[j][ks] = *(const f16x8*)&rh[swz(16 * j + li, ks * 4 + g)];

        #pragma unroll 1
        for (int ch = 0; ch < 2; ++ch) {
            float4 b4 = *(const float4*)(bias + ch * 64 + 16 * wid + 4 * g);
            f32x4 acc[4];
            #pragma unroll
            for (int j = 0; j < 4; ++j) {
                acc[j][0] = b4.x; acc[j][1] = b4.y; acc[j][2] = b4.z; acc[j][3] = b4.w;
            }
            __builtin_amdgcn_s_setprio(1);
            #pragma unroll
            for (int ks = 0; ks < 4; ++ks) {
                const float* wp = W + (size_t)(ch * 64 + 16 * wid + li) * DDIM + ks * 32 + g * 8;
                f16x8 Af = cvt8(*(const float4*)wp, *(const float4*)(wp + 4));
                #pragma unroll
                for (int j = 0; j < 4; ++j)
                    acc[j] = __builtin_amdgcn_mfma_f32_16x16x32_f16(Af, Yf[j][ks], acc[j], 0, 0, 0);
            }
            __builtin_amdgcn_s_setprio(0);
            int obase = ch * 64 + 16 * wid + 4 * g;
            #pragma unroll
            for (int j = 0; j < 4; ++j)
                *(float4*)(out + (size_t)(p0 + 16 * j + li) * DDIM + obase) =
                    make_float4(acc[j][0], acc[j][1], acc[j][2], acc[j][3]);
        }
    }

    // ---- commit loss: wave shuffle-reduce + block atomic ----
    {
        float cp = commit_part;
        #pragma unroll
        for (int m = 1; m <= 32; m <<= 1) cp += __shfl_xor(cp, m);
        __syncthreads();
        float* wsum = (float*)cand;
        if (lane == 0) wsum[wid] = cp;
        __syncthreads();
        if (tid == 0) {
            float t = (wsum[0] + wsum[1]) + (wsum[2] + wsum[3]);
            atomicAdd(out + (size_t)NPTS * DDIM + NPTS,
                      t * (1.0f / ((float)NPTS * (float)DDIM)));
        }
    }
}

// ---------------------------------------------------------------------------
extern "C" void kernel_launch(void* const* d_in, const int* in_sizes, int n_in,
                              void* d_out, int out_size, void* d_ws, size_t ws_size,
                              hipStream_t stream) {
    const float* x    = (const float*)d_in[0];
    const float* cb   = (const float*)d_in[1];
    const float* linw = (const float*)d_in[2];
    const float* linb = (const float*)d_in[3];
    float* out    = (float*)d_out;
    float* norms  = (float*)d_ws;                        // 3072 f
    float* ascore = norms + 4096;                        // 3072 f
    f16*   cb16   = (f16*)((char*)d_ws + 32768);         // 786432 B
    const size_t need = 32768 + (size_t)NVQ * KCODES * DDIM * 2;

    zero_commit_kernel<<<1, 1, 0, stream>>>(out + (size_t)NPTS * DDIM + NPTS);
    norms_kernel<<<NVQ * KCODES, 64, 0, stream>>>(cb, norms, ascore);

    if (ws_size >= need) {
        preconv_kernel<<<(NVQ * KCODES * DDIM) / (256 * 8), 256, 0, stream>>>(cb, cb16);
        rvq_kernel<true><<<NPTS / TM, BLOCKT, 0, stream>>>(x, cb, cb16, linw, linb,
                                                           norms, ascore, out);
    } else {
        rvq_kernel<false><<<NPTS / TM, BLOCKT, 0, stream>>>(x, cb, cb16, linw, linb,
                                                            norms, ascore, out);
    }
}